// Round 1
// baseline (18491.496 us; speedup 1.0000x reference)
//
#include <hip/hip_runtime.h>

#define N_S 400000
#define N_F 128
#define N_K 512
#define ITERS 10

// ---------------------------------------------------------------------------
// init: copy init_centroids into the working centroid buffer (d_out region)
// ---------------------------------------------------------------------------
__global__ __launch_bounds__(256) void init_cent_kernel(const float* __restrict__ src,
                                                        float* __restrict__ cent) {
    int i = blockIdx.x * 256 + threadIdx.x;
    if (i < N_K * N_F) cent[i] = src[i];
}

// ---------------------------------------------------------------------------
// prep (per iter): c_sq[k] = ||cent_k||^2 ; zero sums/counts/inertia
// 512 blocks x 64 threads (1 wave per cluster)
// ---------------------------------------------------------------------------
__global__ __launch_bounds__(64) void prep_kernel(const float* __restrict__ cent,
                                                  float* __restrict__ c_sq,
                                                  float* __restrict__ sums,
                                                  float* __restrict__ counts,
                                                  float* __restrict__ inertia) {
    int k = blockIdx.x;
    int lane = threadIdx.x;
    float a = cent[k * N_F + lane];
    float b = cent[k * N_F + 64 + lane];
    float s = fmaf(a, a, b * b);
#pragma unroll
    for (int off = 32; off > 0; off >>= 1) s += __shfl_down(s, off);
    if (lane == 0) {
        c_sq[k] = s;
        counts[k] = 0.f;
    }
    sums[k * N_F + lane] = 0.f;
    sums[k * N_F + 64 + lane] = 0.f;
    if (k == 0 && lane == 0) *inertia = 0.f;
}

// ---------------------------------------------------------------------------
// assign (per iter, dominant): d2 = x_sq - 2*x.c + c_sq ; argmin/min over K.
// One thread per sample; X row held in 128 VGPRs; cluster loop unrolled x4;
// centroid reads are wave-uniform -> scalar loads, loop stays FMA-bound.
// ---------------------------------------------------------------------------
__global__ __launch_bounds__(256) void assign_kernel(const float* __restrict__ X,
                                                     const float* __restrict__ cent,
                                                     const float* __restrict__ c_sq,
                                                     float* __restrict__ labels,
                                                     float* __restrict__ inertia) {
    int i = blockIdx.x * 256 + threadIdx.x;
    bool active = (i < N_S);
    int src = active ? i : 0;

    float x[N_F];
    const float4* xp = (const float4*)(X + (long long)src * N_F);
#pragma unroll
    for (int q = 0; q < N_F / 4; ++q) {
        float4 v = xp[q];
        x[4 * q + 0] = v.x;
        x[4 * q + 1] = v.y;
        x[4 * q + 2] = v.z;
        x[4 * q + 3] = v.w;
    }
    float x_sq = 0.f;
#pragma unroll
    for (int d = 0; d < N_F; ++d) x_sq = fmaf(x[d], x[d], x_sq);

    float best = 3.4e38f;
    int bestk = 0;
    for (int kg = 0; kg < N_K / 4; ++kg) {
        const float* c0 = cent + (4 * kg + 0) * N_F;
        const float* c1 = cent + (4 * kg + 1) * N_F;
        const float* c2 = cent + (4 * kg + 2) * N_F;
        const float* c3 = cent + (4 * kg + 3) * N_F;
        float d0 = 0.f, d1 = 0.f, d2 = 0.f, d3 = 0.f;
#pragma unroll
        for (int d = 0; d < N_F; ++d) {
            float xv = x[d];
            d0 = fmaf(xv, c0[d], d0);
            d1 = fmaf(xv, c1[d], d1);
            d2 = fmaf(xv, c2[d], d2);
            d3 = fmaf(xv, c3[d], d3);
        }
        float t0 = x_sq - 2.f * d0 + c_sq[4 * kg + 0];
        float t1 = x_sq - 2.f * d1 + c_sq[4 * kg + 1];
        float t2 = x_sq - 2.f * d2 + c_sq[4 * kg + 2];
        float t3 = x_sq - 2.f * d3 + c_sq[4 * kg + 3];
        // strict < in ascending k order == first-occurrence argmin (matches ref)
        if (t0 < best) { best = t0; bestk = 4 * kg + 0; }
        if (t1 < best) { best = t1; bestk = 4 * kg + 1; }
        if (t2 < best) { best = t2; bestk = 4 * kg + 2; }
        if (t3 < best) { best = t3; bestk = 4 * kg + 3; }
    }

    if (active) labels[i] = (float)bestk;

    float contrib = active ? fmaxf(best, 0.f) : 0.f;
#pragma unroll
    for (int off = 32; off > 0; off >>= 1) contrib += __shfl_down(contrib, off);
    __shared__ float red[4];
    if ((threadIdx.x & 63) == 0) red[threadIdx.x >> 6] = contrib;
    __syncthreads();
    if (threadIdx.x == 0) atomicAdd(inertia, red[0] + red[1] + red[2] + red[3]);
}

// ---------------------------------------------------------------------------
// sums (per iter): cluster-major segment-sum. Grid = 512 clusters x 8 stripes,
// 1 wave per block. Scan labels coalesced, ballot matches, gather matched rows
// as coalesced float2; one atomicAdd per feature per block at the end.
// ---------------------------------------------------------------------------
#define STRIPES 8
__global__ __launch_bounds__(64) void sums_kernel(const float* __restrict__ X,
                                                  const float* __restrict__ labels,
                                                  float* __restrict__ sums,
                                                  float* __restrict__ counts) {
    int k = blockIdx.x >> 3;       // cluster
    int stripe = blockIdx.x & 7;   // sample stripe
    int lane = threadIdx.x;
    const int per = N_S / STRIPES; // 50000
    int base = stripe * per;
    int end = base + per;
    float fk = (float)k;

    float acc0 = 0.f, acc1 = 0.f;
    float cnt = 0.f;
    for (int s = base; s < end; s += 64) {
        int idx = s + lane;
        float lab = (idx < end) ? labels[idx] : -1.f;
        unsigned long long m = __ballot(lab == fk);
        if (lane == 0) cnt += (float)__popcll(m);
        while (m) {
            int b = __ffsll((long long)m) - 1;
            m &= (m - 1);
            float2 v = ((const float2*)X)[(s + b) * 64 + lane];
            acc0 += v.x;
            acc1 += v.y;
        }
    }
    atomicAdd(&sums[k * N_F + 2 * lane + 0], acc0);
    atomicAdd(&sums[k * N_F + 2 * lane + 1], acc1);
    if (lane == 0) atomicAdd(&counts[k], cnt);
}

// ---------------------------------------------------------------------------
// update (per iter): cent = counts>0 ? sums/counts : old cent (in place)
// ---------------------------------------------------------------------------
__global__ __launch_bounds__(128) void update_kernel(const float* __restrict__ sums,
                                                     const float* __restrict__ counts,
                                                     float* __restrict__ cent) {
    int k = blockIdx.x;
    int d = threadIdx.x;
    float c = counts[k];
    float s = sums[k * N_F + d];
    float old = cent[k * N_F + d];
    cent[k * N_F + d] = (c > 0.f) ? (s / c) : old;
}

extern "C" void kernel_launch(void* const* d_in, const int* in_sizes, int n_in,
                              void* d_out, int out_size, void* d_ws, size_t ws_size,
                              hipStream_t stream) {
    const float* X = (const float*)d_in[0];
    const float* initc = (const float*)d_in[1];

    float* out = (float*)d_out;
    float* cent = out;                 // [512*128] final centroids, working buffer
    float* labels = out + N_K * N_F;   // [400000] float-encoded int labels
    float* inertia = labels + N_S;     // [1]

    float* c_sq = (float*)d_ws;        // [512]
    float* sums = c_sq + N_K;          // [512*128]
    float* counts = sums + N_K * N_F;  // [512]

    init_cent_kernel<<<(N_K * N_F + 255) / 256, 256, 0, stream>>>(initc, cent);
    for (int it = 0; it < ITERS; ++it) {
        prep_kernel<<<N_K, 64, 0, stream>>>(cent, c_sq, sums, counts, inertia);
        assign_kernel<<<(N_S + 255) / 256, 256, 0, stream>>>(X, cent, c_sq, labels, inertia);
        sums_kernel<<<N_K * STRIPES, 64, 0, stream>>>(X, labels, sums, counts);
        update_kernel<<<N_K, N_F, 0, stream>>>(sums, counts, cent);
    }
}

// Round 2
// 5367.030 us; speedup vs baseline: 3.4454x; 3.4454x over previous
//
#include <hip/hip_runtime.h>

#define N_S 400000
#define N_F 128
#define N_K 512
#define ITERS 10

typedef __attribute__((ext_vector_type(8))) short short8;
typedef __attribute__((ext_vector_type(4))) float floatx4;

__device__ inline unsigned short f2bf(float f) {
    unsigned int u = __float_as_uint(f);
    unsigned int r = (u + 0x7FFFu + ((u >> 16) & 1u)) >> 16;
    return (unsigned short)r;
}
__device__ inline float bf2f(unsigned short h) {
    return __uint_as_float(((unsigned int)h) << 16);
}

// ---------------------------------------------------------------------------
// init: copy init_centroids into the working centroid buffer (d_out region)
// ---------------------------------------------------------------------------
__global__ __launch_bounds__(256) void init_cent_kernel(const float* __restrict__ src,
                                                        float* __restrict__ cent) {
    int i = blockIdx.x * 256 + threadIdx.x;
    if (i < N_K * N_F) cent[i] = src[i];
}

// ---------------------------------------------------------------------------
// xsq (once per launch): x_sq[i] = ||X_i||^2, fp32 exact (matches ref).
// 4 waves/block, each wave does 16 rows, 4 lanes per row.
// ---------------------------------------------------------------------------
__global__ __launch_bounds__(256) void xsq_kernel(const float* __restrict__ X,
                                                  float* __restrict__ xsq) {
    int wave = threadIdx.x >> 6, lane = threadIdx.x & 63;
    int row = blockIdx.x * 64 + wave * 16 + (lane >> 2);
    int qpart = lane & 3;
    const float4* xp = (const float4*)(X + (long long)row * N_F) + qpart * 8;
    float s = 0.f;
#pragma unroll
    for (int q = 0; q < 8; ++q) {
        float4 v = xp[q];
        s += v.x * v.x + v.y * v.y + v.z * v.z + v.w * v.w;
    }
    s += __shfl_xor(s, 1);
    s += __shfl_xor(s, 2);
    if (qpart == 0) xsq[row] = s;
}

// ---------------------------------------------------------------------------
// prep (per iter): c_sq[k] (fp32), bf16 hi/lo split of centroids,
// zero sums/counts/inertia. 512 blocks x 64 threads.
// ---------------------------------------------------------------------------
__global__ __launch_bounds__(64) void prep_kernel(const float* __restrict__ cent,
                                                  float* __restrict__ c_sq,
                                                  unsigned short* __restrict__ chi,
                                                  unsigned short* __restrict__ clo,
                                                  float* __restrict__ sums,
                                                  float* __restrict__ counts,
                                                  float* __restrict__ inertia) {
    int k = blockIdx.x;
    int lane = threadIdx.x;
    float a = cent[k * N_F + lane];
    float b = cent[k * N_F + 64 + lane];
    unsigned short ha = f2bf(a), hb = f2bf(b);
    chi[k * N_F + lane] = ha;
    chi[k * N_F + 64 + lane] = hb;
    clo[k * N_F + lane] = f2bf(a - bf2f(ha));
    clo[k * N_F + 64 + lane] = f2bf(b - bf2f(hb));
    float s = fmaf(a, a, b * b);
#pragma unroll
    for (int off = 32; off > 0; off >>= 1) s += __shfl_down(s, off);
    if (lane == 0) {
        c_sq[k] = s;
        counts[k] = 0.f;
    }
    sums[k * N_F + lane] = 0.f;
    sums[k * N_F + 64 + lane] = 0.f;
    if (k == 0 && lane == 0) *inertia = 0.f;
}

// ---------------------------------------------------------------------------
// assign via MFMA (split bf16: chi*xhi + chi*xlo + clo*xhi ~ fp32 dot).
// GEMM: M=clusters (chunks of 32), N=samples (64/block, 16/wave), K=D=128.
// C/D layout: col(=sample)=lane&15 fixed per lane -> per-lane running argmin,
// final 4-lane shfl_xor combine. LDS ~52KB -> 3 blocks/CU.
// ---------------------------------------------------------------------------
#define LDP 136  // padded row stride (elements): +8 keeps b128 align, banks 2-way
#define CHUNK 32
#define NCHUNK (N_K / CHUNK)

__global__ __launch_bounds__(256, 2) void assign_mfma_kernel(
    const float* __restrict__ X,
    const unsigned short* __restrict__ centhi,
    const unsigned short* __restrict__ centlo,
    const float* __restrict__ c_sq,
    const float* __restrict__ x_sq,
    float* __restrict__ labels,
    float* __restrict__ inertia) {
    __shared__ unsigned short xhi[64 * LDP];
    __shared__ unsigned short xlo[64 * LDP];
    __shared__ unsigned short chs[CHUNK * LDP];
    __shared__ unsigned short cls[CHUNK * LDP];
    __shared__ float csq_s[CHUNK];

    int t = threadIdx.x;
    int wave = t >> 6, lane = t & 63;
    int quad = lane >> 4, l15 = lane & 15;
    int S0 = blockIdx.x * 64;

    // ---- stage X tile: fp32 global -> bf16 hi/lo in LDS ----
#pragma unroll
    for (int r = 0; r < 8; ++r) {
        int id = t + 256 * r;    // 2048 float4 groups = 64 rows x 32
        int row = id >> 5;
        int c4 = id & 31;
        float4 v = ((const float4*)(X + (long long)(S0 + row) * N_F))[c4];
        unsigned short h0 = f2bf(v.x), h1 = f2bf(v.y), h2 = f2bf(v.z), h3 = f2bf(v.w);
        ushort4 hv = {h0, h1, h2, h3};
        ushort4 lv = {f2bf(v.x - bf2f(h0)), f2bf(v.y - bf2f(h1)),
                      f2bf(v.z - bf2f(h2)), f2bf(v.w - bf2f(h3))};
        int off = row * LDP + c4 * 4;
        *(ushort4*)&xhi[off] = hv;
        *(ushort4*)&xlo[off] = lv;
    }
    __syncthreads();

    // ---- hoist B fragments (X side), invariant across cluster chunks ----
    int brow = wave * 16 + l15;
    short8 bhi[4], blo[4];
#pragma unroll
    for (int kt = 0; kt < 4; ++kt) {
        int off = brow * LDP + kt * 32 + quad * 8;
        bhi[kt] = *(const short8*)&xhi[off];
        blo[kt] = *(const short8*)&xlo[off];
    }
    float xsq_v = x_sq[S0 + brow];

    float best = 3.4e38f;
    int bestk = 0;

    for (int c = 0; c < NCHUNK; ++c) {
        __syncthreads();  // previous chunk compute done before overwrite
        // ---- stage centroid chunk (bf16 hi/lo, 32 rows) ----
#pragma unroll
        for (int r = 0; r < 2; ++r) {
            int id = t + 256 * r;  // 512 x ushort8 per split
            int row = id >> 4;
            int c8 = id & 15;
            long long g = (long long)(c * CHUNK + row) * N_F + c8 * 8;
            uint4 vh = *(const uint4*)(centhi + g);
            uint4 vl = *(const uint4*)(centlo + g);
            int off = row * LDP + c8 * 8;
            *(uint4*)&chs[off] = vh;
            *(uint4*)&cls[off] = vl;
        }
        if (t < CHUNK) csq_s[t] = c_sq[c * CHUNK + t];
        __syncthreads();

        // ---- MFMA: 2 m-tiles x 4 k-tiles x 3 split products ----
        floatx4 acc[2];
#pragma unroll
        for (int mt = 0; mt < 2; ++mt) acc[mt] = (floatx4){0.f, 0.f, 0.f, 0.f};
#pragma unroll
        for (int kt = 0; kt < 4; ++kt) {
#pragma unroll
            for (int mt = 0; mt < 2; ++mt) {
                int aoff = (mt * 16 + l15) * LDP + kt * 32 + quad * 8;
                short8 ahi = *(const short8*)&chs[aoff];
                short8 alo = *(const short8*)&cls[aoff];
                acc[mt] = __builtin_amdgcn_mfma_f32_16x16x32_bf16(ahi, bhi[kt], acc[mt], 0, 0, 0);
                acc[mt] = __builtin_amdgcn_mfma_f32_16x16x32_bf16(ahi, blo[kt], acc[mt], 0, 0, 0);
                acc[mt] = __builtin_amdgcn_mfma_f32_16x16x32_bf16(alo, bhi[kt], acc[mt], 0, 0, 0);
            }
        }
        // ---- epilogue: fold chunk into running per-lane argmin ----
#pragma unroll
        for (int mt = 0; mt < 2; ++mt) {
#pragma unroll
            for (int r = 0; r < 4; ++r) {
                int kk = mt * 16 + quad * 4 + r;  // row = cluster within chunk
                float d2 = xsq_v - 2.f * acc[mt][r] + csq_s[kk];
                int kg = c * CHUNK + kk;
                if (d2 < best) { best = d2; bestk = kg; }  // per-lane k ascending
            }
        }
    }

    // ---- combine the 4 lanes sharing each sample col (tie -> smaller k) ----
#pragma unroll
    for (int off = 16; off < 64; off <<= 1) {
        float ob = __shfl_xor(best, off);
        int ok = __shfl_xor(bestk, off);
        if (ob < best || (ob == best && ok < bestk)) { best = ob; bestk = ok; }
    }
    if (quad == 0) labels[S0 + wave * 16 + l15] = (float)bestk;

    float contrib = (quad == 0) ? fmaxf(best, 0.f) : 0.f;
#pragma unroll
    for (int off = 32; off > 0; off >>= 1) contrib += __shfl_down(contrib, off);
    __shared__ float red[4];
    if (lane == 0) red[wave] = contrib;
    __syncthreads();
    if (t == 0) atomicAdd(inertia, red[0] + red[1] + red[2] + red[3]);
}

// ---------------------------------------------------------------------------
// sums (per iter): cluster-major segment-sum (unchanged from R1).
// ---------------------------------------------------------------------------
#define STRIPES 8
__global__ __launch_bounds__(64) void sums_kernel(const float* __restrict__ X,
                                                  const float* __restrict__ labels,
                                                  float* __restrict__ sums,
                                                  float* __restrict__ counts) {
    int k = blockIdx.x >> 3;
    int stripe = blockIdx.x & 7;
    int lane = threadIdx.x;
    const int per = N_S / STRIPES;
    int base = stripe * per;
    int end = base + per;
    float fk = (float)k;

    float acc0 = 0.f, acc1 = 0.f;
    float cnt = 0.f;
    for (int s = base; s < end; s += 64) {
        int idx = s + lane;
        float lab = (idx < end) ? labels[idx] : -1.f;
        unsigned long long m = __ballot(lab == fk);
        if (lane == 0) cnt += (float)__popcll(m);
        while (m) {
            int b = __ffsll((long long)m) - 1;
            m &= (m - 1);
            float2 v = ((const float2*)X)[(s + b) * 64 + lane];
            acc0 += v.x;
            acc1 += v.y;
        }
    }
    atomicAdd(&sums[k * N_F + 2 * lane + 0], acc0);
    atomicAdd(&sums[k * N_F + 2 * lane + 1], acc1);
    if (lane == 0) atomicAdd(&counts[k], cnt);
}

// ---------------------------------------------------------------------------
// update (per iter): cent = counts>0 ? sums/counts : old cent (in place)
// ---------------------------------------------------------------------------
__global__ __launch_bounds__(128) void update_kernel(const float* __restrict__ sums,
                                                     const float* __restrict__ counts,
                                                     float* __restrict__ cent) {
    int k = blockIdx.x;
    int d = threadIdx.x;
    float c = counts[k];
    float s = sums[k * N_F + d];
    float old = cent[k * N_F + d];
    cent[k * N_F + d] = (c > 0.f) ? (s / c) : old;
}

extern "C" void kernel_launch(void* const* d_in, const int* in_sizes, int n_in,
                              void* d_out, int out_size, void* d_ws, size_t ws_size,
                              hipStream_t stream) {
    const float* X = (const float*)d_in[0];
    const float* initc = (const float*)d_in[1];

    float* out = (float*)d_out;
    float* cent = out;                // [512*128] working centroids (= output 0)
    float* labels = out + N_K * N_F;  // [400000] float-encoded labels (output 1)
    float* inertia = labels + N_S;    // [1] (output 2)

    float* c_sq = (float*)d_ws;                       // [512]
    float* sums = c_sq + N_K;                         // [512*128]
    float* counts = sums + N_K * N_F;                 // [512]
    float* xsq = counts + N_K;                        // [400000]
    unsigned short* centhi = (unsigned short*)(xsq + N_S);  // [512*128]
    unsigned short* centlo = centhi + N_K * N_F;            // [512*128]

    init_cent_kernel<<<(N_K * N_F + 255) / 256, 256, 0, stream>>>(initc, cent);
    xsq_kernel<<<N_S / 64, 256, 0, stream>>>(X, xsq);
    for (int it = 0; it < ITERS; ++it) {
        prep_kernel<<<N_K, 64, 0, stream>>>(cent, c_sq, centhi, centlo, sums, counts, inertia);
        assign_mfma_kernel<<<N_S / 64, 256, 0, stream>>>(X, centhi, centlo, c_sq, xsq,
                                                         labels, inertia);
        sums_kernel<<<N_K * STRIPES, 64, 0, stream>>>(X, labels, sums, counts);
        update_kernel<<<N_K, N_F, 0, stream>>>(sums, counts, cent);
    }
}

// Round 3
// 5323.647 us; speedup vs baseline: 3.4735x; 1.0081x over previous
//
#include <hip/hip_runtime.h>

#define N_S 400000
#define N_F 128
#define N_K 512
#define ITERS 10

typedef __attribute__((ext_vector_type(8))) short short8;
typedef __attribute__((ext_vector_type(4))) float floatx4;

__device__ inline unsigned short f2bf(float f) {
    unsigned int u = __float_as_uint(f);
    unsigned int r = (u + 0x7FFFu + ((u >> 16) & 1u)) >> 16;
    return (unsigned short)r;
}
__device__ inline float bf2f(unsigned short h) {
    return __uint_as_float(((unsigned int)h) << 16);
}

// ---------------------------------------------------------------------------
// init: copy init_centroids into the working centroid buffer (d_out region)
// ---------------------------------------------------------------------------
__global__ __launch_bounds__(256) void init_cent_kernel(const float* __restrict__ src,
                                                        float* __restrict__ cent) {
    int i = blockIdx.x * 256 + threadIdx.x;
    if (i < N_K * N_F) cent[i] = src[i];
}

// ---------------------------------------------------------------------------
// xsq (once per launch): x_sq[i] = ||X_i||^2, fp32 exact (matches ref).
// ---------------------------------------------------------------------------
__global__ __launch_bounds__(256) void xsq_kernel(const float* __restrict__ X,
                                                  float* __restrict__ xsq) {
    int wave = threadIdx.x >> 6, lane = threadIdx.x & 63;
    int row = blockIdx.x * 64 + wave * 16 + (lane >> 2);
    int qpart = lane & 3;
    const float4* xp = (const float4*)(X + (long long)row * N_F) + qpart * 8;
    float s = 0.f;
#pragma unroll
    for (int q = 0; q < 8; ++q) {
        float4 v = xp[q];
        s += v.x * v.x + v.y * v.y + v.z * v.z + v.w * v.w;
    }
    s += __shfl_xor(s, 1);
    s += __shfl_xor(s, 2);
    if (qpart == 0) xsq[row] = s;
}

// ---------------------------------------------------------------------------
// prep (per iter): c_sq[k] (fp32), bf16 hi/lo split of centroids,
// zero sums/counts/inertia. 512 blocks x 64 threads.
// ---------------------------------------------------------------------------
__global__ __launch_bounds__(64) void prep_kernel(const float* __restrict__ cent,
                                                  float* __restrict__ c_sq,
                                                  unsigned short* __restrict__ chi,
                                                  unsigned short* __restrict__ clo,
                                                  float* __restrict__ sums,
                                                  float* __restrict__ counts,
                                                  float* __restrict__ inertia) {
    int k = blockIdx.x;
    int lane = threadIdx.x;
    float a = cent[k * N_F + lane];
    float b = cent[k * N_F + 64 + lane];
    unsigned short ha = f2bf(a), hb = f2bf(b);
    chi[k * N_F + lane] = ha;
    chi[k * N_F + 64 + lane] = hb;
    clo[k * N_F + lane] = f2bf(a - bf2f(ha));
    clo[k * N_F + 64 + lane] = f2bf(b - bf2f(hb));
    float s = fmaf(a, a, b * b);
#pragma unroll
    for (int off = 32; off > 0; off >>= 1) s += __shfl_down(s, off);
    if (lane == 0) {
        c_sq[k] = s;
        counts[k] = 0.f;
    }
    sums[k * N_F + lane] = 0.f;
    sums[k * N_F + 64 + lane] = 0.f;
    if (k == 0 && lane == 0) *inertia = 0.f;
}

// ---------------------------------------------------------------------------
// assign via MFMA (split bf16: chi*xhi + chi*xlo + clo*xhi ~ fp32 dot).
// Unchanged from R2.
// ---------------------------------------------------------------------------
#define LDP 136
#define CHUNK 32
#define NCHUNK (N_K / CHUNK)

__global__ __launch_bounds__(256, 2) void assign_mfma_kernel(
    const float* __restrict__ X,
    const unsigned short* __restrict__ centhi,
    const unsigned short* __restrict__ centlo,
    const float* __restrict__ c_sq,
    const float* __restrict__ x_sq,
    float* __restrict__ labels,
    float* __restrict__ inertia) {
    __shared__ unsigned short xhi[64 * LDP];
    __shared__ unsigned short xlo[64 * LDP];
    __shared__ unsigned short chs[CHUNK * LDP];
    __shared__ unsigned short cls[CHUNK * LDP];
    __shared__ float csq_s[CHUNK];

    int t = threadIdx.x;
    int wave = t >> 6, lane = t & 63;
    int quad = lane >> 4, l15 = lane & 15;
    int S0 = blockIdx.x * 64;

#pragma unroll
    for (int r = 0; r < 8; ++r) {
        int id = t + 256 * r;
        int row = id >> 5;
        int c4 = id & 31;
        float4 v = ((const float4*)(X + (long long)(S0 + row) * N_F))[c4];
        unsigned short h0 = f2bf(v.x), h1 = f2bf(v.y), h2 = f2bf(v.z), h3 = f2bf(v.w);
        ushort4 hv = {h0, h1, h2, h3};
        ushort4 lv = {f2bf(v.x - bf2f(h0)), f2bf(v.y - bf2f(h1)),
                      f2bf(v.z - bf2f(h2)), f2bf(v.w - bf2f(h3))};
        int off = row * LDP + c4 * 4;
        *(ushort4*)&xhi[off] = hv;
        *(ushort4*)&xlo[off] = lv;
    }
    __syncthreads();

    int brow = wave * 16 + l15;
    short8 bhi[4], blo[4];
#pragma unroll
    for (int kt = 0; kt < 4; ++kt) {
        int off = brow * LDP + kt * 32 + quad * 8;
        bhi[kt] = *(const short8*)&xhi[off];
        blo[kt] = *(const short8*)&xlo[off];
    }
    float xsq_v = x_sq[S0 + brow];

    float best = 3.4e38f;
    int bestk = 0;

    for (int c = 0; c < NCHUNK; ++c) {
        __syncthreads();
#pragma unroll
        for (int r = 0; r < 2; ++r) {
            int id = t + 256 * r;
            int row = id >> 4;
            int c8 = id & 15;
            long long g = (long long)(c * CHUNK + row) * N_F + c8 * 8;
            uint4 vh = *(const uint4*)(centhi + g);
            uint4 vl = *(const uint4*)(centlo + g);
            int off = row * LDP + c8 * 8;
            *(uint4*)&chs[off] = vh;
            *(uint4*)&cls[off] = vl;
        }
        if (t < CHUNK) csq_s[t] = c_sq[c * CHUNK + t];
        __syncthreads();

        floatx4 acc[2];
#pragma unroll
        for (int mt = 0; mt < 2; ++mt) acc[mt] = (floatx4){0.f, 0.f, 0.f, 0.f};
#pragma unroll
        for (int kt = 0; kt < 4; ++kt) {
#pragma unroll
            for (int mt = 0; mt < 2; ++mt) {
                int aoff = (mt * 16 + l15) * LDP + kt * 32 + quad * 8;
                short8 ahi = *(const short8*)&chs[aoff];
                short8 alo = *(const short8*)&cls[aoff];
                acc[mt] = __builtin_amdgcn_mfma_f32_16x16x32_bf16(ahi, bhi[kt], acc[mt], 0, 0, 0);
                acc[mt] = __builtin_amdgcn_mfma_f32_16x16x32_bf16(ahi, blo[kt], acc[mt], 0, 0, 0);
                acc[mt] = __builtin_amdgcn_mfma_f32_16x16x32_bf16(alo, bhi[kt], acc[mt], 0, 0, 0);
            }
        }
#pragma unroll
        for (int mt = 0; mt < 2; ++mt) {
#pragma unroll
            for (int r = 0; r < 4; ++r) {
                int kk = mt * 16 + quad * 4 + r;
                float d2 = xsq_v - 2.f * acc[mt][r] + csq_s[kk];
                int kg = c * CHUNK + kk;
                if (d2 < best) { best = d2; bestk = kg; }
            }
        }
    }

#pragma unroll
    for (int off = 16; off < 64; off <<= 1) {
        float ob = __shfl_xor(best, off);
        int ok = __shfl_xor(bestk, off);
        if (ob < best || (ob == best && ok < bestk)) { best = ob; bestk = ok; }
    }
    if (quad == 0) labels[S0 + wave * 16 + l15] = (float)bestk;

    float contrib = (quad == 0) ? fmaxf(best, 0.f) : 0.f;
#pragma unroll
    for (int off = 32; off > 0; off >>= 1) contrib += __shfl_down(contrib, off);
    __shared__ float red[4];
    if (lane == 0) red[wave] = contrib;
    __syncthreads();
    if (t == 0) atomicAdd(inertia, red[0] + red[1] + red[2] + red[3]);
}

// ---------------------------------------------------------------------------
// sums (per iter): two-phase cluster-group segment-sum.
// Grid = 8 cluster-groups x 64 sample-stripes; block=256, LDS acc 64x128.
// Phase 1: compact matched (sample,cluster) into LDS queue (wave-agg cursor).
// Phase 2: 4 waves drain queue 4-deep -> 8 X-row loads in flight/wave.
// ---------------------------------------------------------------------------
#define SGR 8
#define KG (N_K / SGR)     // 64
#define SST 64
#define PERS (N_S / SST)   // 6250
#define QU 4

__global__ __launch_bounds__(256, 2) void sums_kernel(const float* __restrict__ X,
                                                      const float* __restrict__ labels,
                                                      float* __restrict__ sums,
                                                      float* __restrict__ counts) {
    __shared__ float lsum[KG * N_F];  // 32 KB
    __shared__ float lcnt[KG];
    __shared__ int queue[PERS];       // 25 KB
    __shared__ int qcount;
    int g = blockIdx.x / SST;
    int stripe = blockIdx.x % SST;
    int t = threadIdx.x;
    int wave = t >> 6, lane = t & 63;

    for (int i = t; i < KG * N_F; i += 256) lsum[i] = 0.f;
    if (t < KG) lcnt[t] = 0.f;
    if (t == 0) qcount = 0;
    __syncthreads();

    int base = stripe * PERS;
    int klo = g * KG;
    const int NITER = (PERS + 255) / 256;  // 25
    for (int itr = 0; itr < NITER; ++itr) {
        int idx = base + itr * 256 + t;
        int k = -1;
        if (idx < base + PERS) k = (int)labels[idx];
        int kk = k - klo;
        bool match = (kk >= 0) && (kk < KG);
        unsigned long long m = __ballot(match);
        int nmatch = __popcll(m);
        int prefix = __popcll(m & ((1ull << lane) - 1ull));
        int wbase = 0;
        if (lane == 0 && nmatch) wbase = atomicAdd(&qcount, nmatch);
        wbase = __shfl(wbase, 0);
        if (match) {
            queue[wbase + prefix] = (idx << 6) | kk;
            atomicAdd(&lcnt[kk], 1.f);
        }
    }
    __syncthreads();

    int qn = qcount;
    for (int q = wave * QU; q < qn; q += 4 * QU) {
        int lim = qn - q;
        float v0[QU], v1[QU];
        int kks[QU];
#pragma unroll
        for (int j = 0; j < QU; ++j) {
            if (j < lim) {
                int e = queue[q + j];
                int smp = e >> 6;
                kks[j] = e & 63;
                v0[j] = X[(long long)smp * N_F + lane];
                v1[j] = X[(long long)smp * N_F + 64 + lane];
            }
        }
#pragma unroll
        for (int j = 0; j < QU; ++j) {
            if (j < lim) {
                atomicAdd(&lsum[kks[j] * N_F + lane], v0[j]);
                atomicAdd(&lsum[kks[j] * N_F + 64 + lane], v1[j]);
            }
        }
    }
    __syncthreads();

    for (int i = t; i < KG * N_F; i += 256) atomicAdd(&sums[klo * N_F + i], lsum[i]);
    if (t < KG) atomicAdd(&counts[klo + t], lcnt[t]);
}

// ---------------------------------------------------------------------------
// update (per iter): cent = counts>0 ? sums/counts : old cent (in place)
// ---------------------------------------------------------------------------
__global__ __launch_bounds__(128) void update_kernel(const float* __restrict__ sums,
                                                     const float* __restrict__ counts,
                                                     float* __restrict__ cent) {
    int k = blockIdx.x;
    int d = threadIdx.x;
    float c = counts[k];
    float s = sums[k * N_F + d];
    float old = cent[k * N_F + d];
    cent[k * N_F + d] = (c > 0.f) ? (s / c) : old;
}

extern "C" void kernel_launch(void* const* d_in, const int* in_sizes, int n_in,
                              void* d_out, int out_size, void* d_ws, size_t ws_size,
                              hipStream_t stream) {
    const float* X = (const float*)d_in[0];
    const float* initc = (const float*)d_in[1];

    float* out = (float*)d_out;
    float* cent = out;
    float* labels = out + N_K * N_F;
    float* inertia = labels + N_S;

    float* c_sq = (float*)d_ws;
    float* sums = c_sq + N_K;
    float* counts = sums + N_K * N_F;
    float* xsq = counts + N_K;
    unsigned short* centhi = (unsigned short*)(xsq + N_S);
    unsigned short* centlo = centhi + N_K * N_F;

    init_cent_kernel<<<(N_K * N_F + 255) / 256, 256, 0, stream>>>(initc, cent);
    xsq_kernel<<<N_S / 64, 256, 0, stream>>>(X, xsq);
    for (int it = 0; it < ITERS; ++it) {
        prep_kernel<<<N_K, 64, 0, stream>>>(cent, c_sq, centhi, centlo, sums, counts, inertia);
        assign_mfma_kernel<<<N_S / 64, 256, 0, stream>>>(X, centhi, centlo, c_sq, xsq,
                                                         labels, inertia);
        sums_kernel<<<SGR * SST, 256, 0, stream>>>(X, labels, sums, counts);
        update_kernel<<<N_K, N_F, 0, stream>>>(sums, counts, cent);
    }
}

// Round 4
// 4270.893 us; speedup vs baseline: 4.3297x; 1.2465x over previous
//
#include <hip/hip_runtime.h>

#define N_S 400000
#define N_F 128
#define N_K 512
#define ITERS 10

typedef __attribute__((ext_vector_type(8))) short short8;
typedef __attribute__((ext_vector_type(4))) float floatx4;

__device__ inline unsigned short f2bf(float f) {
    unsigned int u = __float_as_uint(f);
    unsigned int r = (u + 0x7FFFu + ((u >> 16) & 1u)) >> 16;
    return (unsigned short)r;
}
__device__ inline float bf2f(unsigned short h) {
    return __uint_as_float(((unsigned int)h) << 16);
}

// Swizzled (MFMA-fragment-order) centroid storage:
// cluster k, dim d -> frag ((k>>5)*8 + ((k>>4)&1)*4 + (d>>5)), lane quad*16+m, elem j
__device__ inline void put_sw(unsigned short* __restrict__ swhi,
                              unsigned short* __restrict__ swlo,
                              int k, int d, float v) {
    int c = k >> 5, mm = k & 31;
    int mt = mm >> 4, m = mm & 15;
    int kt = d >> 5, r = d & 31;
    int quad = r >> 3, j = r & 7;
    int lane = quad * 16 + m;
    int idx = ((c * 8 + mt * 4 + kt) * 64 + lane) * 8 + j;
    unsigned short h = f2bf(v);
    swhi[idx] = h;
    swlo[idx] = f2bf(v - bf2f(h));
}

// ---------------------------------------------------------------------------
// xsq (once): x_sq[i] = ||X_i||^2 fp32 exact
// ---------------------------------------------------------------------------
__global__ __launch_bounds__(256) void xsq_kernel(const float* __restrict__ X,
                                                  float* __restrict__ xsq) {
    int wave = threadIdx.x >> 6, lane = threadIdx.x & 63;
    int row = blockIdx.x * 64 + wave * 16 + (lane >> 2);
    int qpart = lane & 3;
    const float4* xp = (const float4*)(X + (long long)row * N_F) + qpart * 8;
    float s = 0.f;
#pragma unroll
    for (int q = 0; q < 8; ++q) {
        float4 v = xp[q];
        s += v.x * v.x + v.y * v.y + v.z * v.z + v.w * v.w;
    }
    s += __shfl_xor(s, 1);
    s += __shfl_xor(s, 2);
    if (qpart == 0) xsq[row] = s;
}

// ---------------------------------------------------------------------------
// prep_update (per iter): [optional] cent = counts>0 ? sums/counts : cent;
// write fp32 cent, c_sq, swizzled bf16 hi/lo; zero sums/ihist/inertia.
// ---------------------------------------------------------------------------
__global__ __launch_bounds__(64) void prep_update_kernel(
    const float* __restrict__ src, float* __restrict__ cent,
    float* __restrict__ sums, const float* __restrict__ counts_f,
    float* __restrict__ c_sq,
    unsigned short* __restrict__ swhi, unsigned short* __restrict__ swlo,
    int* __restrict__ ihist, float* __restrict__ inertia, int do_update) {
    int k = blockIdx.x, lane = threadIdx.x;
    float a, b;
    if (do_update) {
        float cnt = counts_f[k];
        float sa = sums[k * N_F + lane], sb = sums[k * N_F + 64 + lane];
        float olda = cent[k * N_F + lane], oldb = cent[k * N_F + 64 + lane];
        a = (cnt > 0.f) ? (sa / cnt) : olda;
        b = (cnt > 0.f) ? (sb / cnt) : oldb;
    } else {
        a = src[k * N_F + lane];
        b = src[k * N_F + 64 + lane];
    }
    cent[k * N_F + lane] = a;
    cent[k * N_F + 64 + lane] = b;
    sums[k * N_F + lane] = 0.f;
    sums[k * N_F + 64 + lane] = 0.f;
    put_sw(swhi, swlo, k, lane, a);
    put_sw(swhi, swlo, k, lane + 64, b);
    float s = fmaf(a, a, b * b);
#pragma unroll
    for (int off = 32; off > 0; off >>= 1) s += __shfl_down(s, off);
    if (lane == 0) {
        c_sq[k] = s;
        ihist[k] = 0;
        if (k == 0) *inertia = 0.f;
    }
}

// ---------------------------------------------------------------------------
// assign (per iter, dominant): 128 samples/block, 32/wave (2 n-tiles).
// B-frags (X) direct global->regs; A (centroids) fragment-ordered LDS,
// ds_read_b128 at lane*16 (0 conflicts). 3-product split-bf16 MFMA.
// Fused: labels, inertia, and LDS->global label histogram.
// ---------------------------------------------------------------------------
#define CHUNK 32
#define NCHUNK (N_K / CHUNK)

__global__ __launch_bounds__(256, 3) void assign_kernel(
    const float* __restrict__ X,
    const unsigned short* __restrict__ swhi,
    const unsigned short* __restrict__ swlo,
    const float* __restrict__ c_sq,
    const float* __restrict__ x_sq,
    float* __restrict__ labels,
    float* __restrict__ inertia,
    int* __restrict__ ihist) {
    __shared__ __align__(16) unsigned short As[8192];  // [0:4096)=hi, [4096:8192)=lo
    __shared__ float csq_s[CHUNK];
    __shared__ int lhist[N_K];
    __shared__ float red[4];

    int t = threadIdx.x;
    int w = t >> 6, l = t & 63;
    int quad = l >> 4, l15 = l & 15;
    long long S0 = (long long)blockIdx.x * 128;

    for (int i = t; i < N_K; i += 256) lhist[i] = 0;

    // B fragments + xsq, direct from global
    short8 bhi[2][4], blo[2][4];
    float xsqv[2];
#pragma unroll
    for (int nt = 0; nt < 2; ++nt) {
        long long s = S0 + w * 32 + nt * 16 + l15;
        xsqv[nt] = x_sq[s];
        const float4* xp = (const float4*)(X + s * N_F);
#pragma unroll
        for (int kt = 0; kt < 4; ++kt) {
            float4 va = xp[kt * 8 + quad * 2];
            float4 vb = xp[kt * 8 + quad * 2 + 1];
            float f[8] = {va.x, va.y, va.z, va.w, vb.x, vb.y, vb.z, vb.w};
            short8 h, lo8;
#pragma unroll
            for (int j = 0; j < 8; ++j) {
                unsigned short hh = f2bf(f[j]);
                h[j] = (short)hh;
                lo8[j] = (short)f2bf(f[j] - bf2f(hh));
            }
            bhi[nt][kt] = h;
            blo[nt][kt] = lo8;
        }
    }

    float best[2] = {3.4e38f, 3.4e38f};
    int bestk[2] = {0, 0};

    for (int c = 0; c < NCHUNK; ++c) {
        __syncthreads();
        // stage chunk: 8KB hi + 8KB lo, fragment-ordered (plain lane-linear copy)
        {
            const uint4* gh = (const uint4*)(swhi + (size_t)c * 4096);
            const uint4* gl = (const uint4*)(swlo + (size_t)c * 4096);
            uint4* lh = (uint4*)As;
            lh[t] = gh[t];
            lh[256 + t] = gh[256 + t];
            lh[512 + t] = gl[t];
            lh[768 + t] = gl[256 + t];
        }
        if (t < CHUNK) csq_s[t] = c_sq[c * CHUNK + t];
        __syncthreads();

        floatx4 acc[2][2];
#pragma unroll
        for (int mt = 0; mt < 2; ++mt)
#pragma unroll
            for (int nt = 0; nt < 2; ++nt) acc[mt][nt] = (floatx4){0.f, 0.f, 0.f, 0.f};

#pragma unroll
        for (int kt = 0; kt < 4; ++kt) {
#pragma unroll
            for (int mt = 0; mt < 2; ++mt) {
                int fo = (mt * 4 + kt) * 512 + l * 8;
                short8 ah = *(const short8*)&As[fo];
                short8 al = *(const short8*)&As[4096 + fo];
#pragma unroll
                for (int nt = 0; nt < 2; ++nt) {
                    acc[mt][nt] = __builtin_amdgcn_mfma_f32_16x16x32_bf16(ah, bhi[nt][kt], acc[mt][nt], 0, 0, 0);
                    acc[mt][nt] = __builtin_amdgcn_mfma_f32_16x16x32_bf16(ah, blo[nt][kt], acc[mt][nt], 0, 0, 0);
                    acc[mt][nt] = __builtin_amdgcn_mfma_f32_16x16x32_bf16(al, bhi[nt][kt], acc[mt][nt], 0, 0, 0);
                }
            }
        }
#pragma unroll
        for (int mt = 0; mt < 2; ++mt) {
#pragma unroll
            for (int r = 0; r < 4; ++r) {
                float cs = csq_s[mt * 16 + quad * 4 + r];
                int kg = c * CHUNK + mt * 16 + quad * 4 + r;
#pragma unroll
                for (int nt = 0; nt < 2; ++nt) {
                    float d2 = xsqv[nt] - 2.f * acc[mt][nt][r] + cs;
                    if (d2 < best[nt]) { best[nt] = d2; bestk[nt] = kg; }
                }
            }
        }
    }

    // combine the 4 quads per sample column (tie -> smaller k)
#pragma unroll
    for (int nt = 0; nt < 2; ++nt) {
#pragma unroll
        for (int off = 16; off < 64; off <<= 1) {
            float ob = __shfl_xor(best[nt], off);
            int ok = __shfl_xor(bestk[nt], off);
            if (ob < best[nt] || (ob == best[nt] && ok < bestk[nt])) {
                best[nt] = ob;
                bestk[nt] = ok;
            }
        }
    }
    if (quad == 0) {
#pragma unroll
        for (int nt = 0; nt < 2; ++nt) {
            labels[S0 + w * 32 + nt * 16 + l15] = (float)bestk[nt];
            atomicAdd(&lhist[bestk[nt]], 1);
        }
    }

    float contrib = (quad == 0) ? (fmaxf(best[0], 0.f) + fmaxf(best[1], 0.f)) : 0.f;
#pragma unroll
    for (int off = 32; off > 0; off >>= 1) contrib += __shfl_down(contrib, off);
    if (l == 0) red[w] = contrib;
    __syncthreads();
    if (t == 0) atomicAdd(inertia, red[0] + red[1] + red[2] + red[3]);

    for (int i = t; i < N_K; i += 256) {
        int v = lhist[i];
        if (v) atomicAdd(&ihist[i], v);
    }
}

// ---------------------------------------------------------------------------
// scan (per iter, 1 block): exclusive prefix of ihist -> offsets, cursor;
// counts as float.
// ---------------------------------------------------------------------------
__global__ __launch_bounds__(512) void scan_kernel(const int* __restrict__ ihist,
                                                   int* __restrict__ offsets,
                                                   int* __restrict__ cursor,
                                                   float* __restrict__ counts_f) {
    __shared__ int tmp[N_K];
    int t = threadIdx.x;
    int v = ihist[t];
    counts_f[t] = (float)v;
    int x = v;
    tmp[t] = x;
    __syncthreads();
    for (int off = 1; off < N_K; off <<= 1) {
        int y = (t >= off) ? tmp[t - off] : 0;
        __syncthreads();
        x += y;
        tmp[t] = x;
        __syncthreads();
    }
    int excl = x - v;
    offsets[t] = excl;
    cursor[t] = excl;
}

// ---------------------------------------------------------------------------
// scatter (per iter): order[cursor[label]++] = sample
// ---------------------------------------------------------------------------
__global__ __launch_bounds__(256) void scatter_kernel(const float* __restrict__ labels,
                                                      int* __restrict__ cursor,
                                                      int* __restrict__ order) {
    int i = blockIdx.x * 256 + threadIdx.x;
    if (i < N_S) {
        int k = (int)labels[i];
        int pos = atomicAdd(&cursor[k], 1);
        order[pos] = i;
    }
}

// ---------------------------------------------------------------------------
// csum (per iter): per cluster-half block sums its contiguous order[] range.
// 2 row-streams x 128 dims, 4-deep pipelined coalesced row gathers.
// ---------------------------------------------------------------------------
#define CSPLIT 2
__global__ __launch_bounds__(256) void csum_kernel(const float* __restrict__ X,
                                                   const int* __restrict__ order,
                                                   const int* __restrict__ offsets,
                                                   const int* __restrict__ ihist,
                                                   float* __restrict__ sums) {
    __shared__ float ls[256];
    int k = blockIdx.x >> 1, half = blockIdx.x & 1;
    int t = threadIdx.x;
    int st = t >> 7, d = t & 127;
    int cnt = ihist[k];
    int start = offsets[k];
    int lo = start + (cnt * half) / CSPLIT;
    int hiE = start + (cnt * (half + 1)) / CSPLIT;

    float acc = 0.f;
    int r = lo + st;
    for (; r + 6 < hiE; r += 8) {
        int o0 = order[r], o1 = order[r + 2], o2 = order[r + 4], o3 = order[r + 6];
        float v0 = X[(long long)o0 * N_F + d];
        float v1 = X[(long long)o1 * N_F + d];
        float v2 = X[(long long)o2 * N_F + d];
        float v3 = X[(long long)o3 * N_F + d];
        acc += v0 + v1 + v2 + v3;
    }
    for (; r < hiE; r += 2) acc += X[(long long)order[r] * N_F + d];

    ls[t] = acc;
    __syncthreads();
    if (t < 128) {
        float s = ls[t] + ls[128 + t];
        atomicAdd(&sums[k * N_F + t], s);
    }
}

// ---------------------------------------------------------------------------
// final update: cent = counts>0 ? sums/counts : cent
// ---------------------------------------------------------------------------
__global__ __launch_bounds__(128) void update_kernel(const float* __restrict__ sums,
                                                     const float* __restrict__ counts_f,
                                                     float* __restrict__ cent) {
    int k = blockIdx.x;
    int d = threadIdx.x;
    float c = counts_f[k];
    float s = sums[k * N_F + d];
    float old = cent[k * N_F + d];
    cent[k * N_F + d] = (c > 0.f) ? (s / c) : old;
}

extern "C" void kernel_launch(void* const* d_in, const int* in_sizes, int n_in,
                              void* d_out, int out_size, void* d_ws, size_t ws_size,
                              hipStream_t stream) {
    const float* X = (const float*)d_in[0];
    const float* initc = (const float*)d_in[1];

    float* out = (float*)d_out;
    float* cent = out;                // [512*128] (output 0)
    float* labels = out + N_K * N_F;  // [400000]  (output 1)
    float* inertia = labels + N_S;    // [1]       (output 2)

    float* c_sq = (float*)d_ws;                      // 512 f
    float* sums = c_sq + N_K;                        // 65536 f
    float* counts_f = sums + N_K * N_F;              // 512 f
    float* xsq = counts_f + N_K;                     // 400000 f
    unsigned short* swhi = (unsigned short*)(xsq + N_S);  // 65536 ush
    unsigned short* swlo = swhi + N_K * N_F;              // 65536 ush
    int* ihist = (int*)(swlo + N_K * N_F);           // 512 i
    int* offsets = ihist + N_K;                      // 512 i
    int* cursor = offsets + N_K;                     // 512 i
    int* order = cursor + N_K;                       // 400000 i

    xsq_kernel<<<N_S / 64, 256, 0, stream>>>(X, xsq);
    for (int it = 0; it < ITERS; ++it) {
        prep_update_kernel<<<N_K, 64, 0, stream>>>(initc, cent, sums, counts_f, c_sq,
                                                   swhi, swlo, ihist, inertia, it > 0);
        assign_kernel<<<N_S / 128, 256, 0, stream>>>(X, swhi, swlo, c_sq, xsq,
                                                     labels, inertia, ihist);
        scan_kernel<<<1, N_K, 0, stream>>>(ihist, offsets, cursor, counts_f);
        scatter_kernel<<<(N_S + 255) / 256, 256, 0, stream>>>(labels, cursor, order);
        csum_kernel<<<N_K * CSPLIT, 256, 0, stream>>>(X, order, offsets, ihist, sums);
    }
    update_kernel<<<N_K, N_F, 0, stream>>>(sums, counts_f, cent);
}

// Round 5
// 2628.014 us; speedup vs baseline: 7.0363x; 1.6251x over previous
//
#include <hip/hip_runtime.h>

#define N_S 400000
#define N_F 128
#define N_K 512
#define ITERS 10

typedef __attribute__((ext_vector_type(8))) short short8;
typedef __attribute__((ext_vector_type(4))) float floatx4;

__device__ inline unsigned short f2bf(float f) {
    unsigned int u = __float_as_uint(f);
    unsigned int r = (u + 0x7FFFu + ((u >> 16) & 1u)) >> 16;
    return (unsigned short)r;
}
__device__ inline float bf2f(unsigned short h) {
    return __uint_as_float(((unsigned int)h) << 16);
}

// Swizzled (MFMA-fragment-order) centroid storage:
// cluster k, dim d -> frag ((k>>5)*8 + ((k>>4)&1)*4 + (d>>5)), lane quad*16+m, elem j
__device__ inline void put_sw(unsigned short* __restrict__ swhi,
                              unsigned short* __restrict__ swlo,
                              int k, int d, float v) {
    int c = k >> 5, mm = k & 31;
    int mt = mm >> 4, m = mm & 15;
    int kt = d >> 5, r = d & 31;
    int quad = r >> 3, j = r & 7;
    int lane = quad * 16 + m;
    int idx = ((c * 8 + mt * 4 + kt) * 64 + lane) * 8 + j;
    unsigned short h = f2bf(v);
    swhi[idx] = h;
    swlo[idx] = f2bf(v - bf2f(h));
}

// ---------------------------------------------------------------------------
// xsq (once): x_sq[i] = ||X_i||^2 fp32 exact
// ---------------------------------------------------------------------------
__global__ __launch_bounds__(256) void xsq_kernel(const float* __restrict__ X,
                                                  float* __restrict__ xsq) {
    int wave = threadIdx.x >> 6, lane = threadIdx.x & 63;
    int row = blockIdx.x * 64 + wave * 16 + (lane >> 2);
    int qpart = lane & 3;
    const float4* xp = (const float4*)(X + (long long)row * N_F) + qpart * 8;
    float s = 0.f;
#pragma unroll
    for (int q = 0; q < 8; ++q) {
        float4 v = xp[q];
        s += v.x * v.x + v.y * v.y + v.z * v.z + v.w * v.w;
    }
    s += __shfl_xor(s, 1);
    s += __shfl_xor(s, 2);
    if (qpart == 0) xsq[row] = s;
}

// ---------------------------------------------------------------------------
// prep_update (per iter): [optional] cent = counts>0 ? sums/counts : cent;
// write fp32 cent, c_sq, swizzled bf16 hi/lo; zero sums/ihist/inertia.
// ---------------------------------------------------------------------------
__global__ __launch_bounds__(64) void prep_update_kernel(
    const float* __restrict__ src, float* __restrict__ cent,
    float* __restrict__ sums, const float* __restrict__ counts_f,
    float* __restrict__ c_sq,
    unsigned short* __restrict__ swhi, unsigned short* __restrict__ swlo,
    int* __restrict__ ihist, float* __restrict__ inertia, int do_update) {
    int k = blockIdx.x, lane = threadIdx.x;
    float a, b;
    if (do_update) {
        float cnt = counts_f[k];
        float sa = sums[k * N_F + lane], sb = sums[k * N_F + 64 + lane];
        float olda = cent[k * N_F + lane], oldb = cent[k * N_F + 64 + lane];
        a = (cnt > 0.f) ? (sa / cnt) : olda;
        b = (cnt > 0.f) ? (sb / cnt) : oldb;
    } else {
        a = src[k * N_F + lane];
        b = src[k * N_F + 64 + lane];
    }
    cent[k * N_F + lane] = a;
    cent[k * N_F + 64 + lane] = b;
    sums[k * N_F + lane] = 0.f;
    sums[k * N_F + 64 + lane] = 0.f;
    put_sw(swhi, swlo, k, lane, a);
    put_sw(swhi, swlo, k, lane + 64, b);
    float s = fmaf(a, a, b * b);
#pragma unroll
    for (int off = 32; off > 0; off >>= 1) s += __shfl_down(s, off);
    if (lane == 0) {
        c_sq[k] = s;
        ihist[k] = 0;
        if (k == 0) *inertia = 0.f;
    }
}

// ---------------------------------------------------------------------------
// assign (per iter): unchanged from R4 (MFMA split-bf16, fused hist/inertia).
// ---------------------------------------------------------------------------
#define CHUNK 32
#define NCHUNK (N_K / CHUNK)

__global__ __launch_bounds__(256, 3) void assign_kernel(
    const float* __restrict__ X,
    const unsigned short* __restrict__ swhi,
    const unsigned short* __restrict__ swlo,
    const float* __restrict__ c_sq,
    const float* __restrict__ x_sq,
    float* __restrict__ labels,
    float* __restrict__ inertia,
    int* __restrict__ ihist) {
    __shared__ __align__(16) unsigned short As[8192];
    __shared__ float csq_s[CHUNK];
    __shared__ int lhist[N_K];
    __shared__ float red[4];

    int t = threadIdx.x;
    int w = t >> 6, l = t & 63;
    int quad = l >> 4, l15 = l & 15;
    long long S0 = (long long)blockIdx.x * 128;

    for (int i = t; i < N_K; i += 256) lhist[i] = 0;

    short8 bhi[2][4], blo[2][4];
    float xsqv[2];
#pragma unroll
    for (int nt = 0; nt < 2; ++nt) {
        long long s = S0 + w * 32 + nt * 16 + l15;
        xsqv[nt] = x_sq[s];
        const float4* xp = (const float4*)(X + s * N_F);
#pragma unroll
        for (int kt = 0; kt < 4; ++kt) {
            float4 va = xp[kt * 8 + quad * 2];
            float4 vb = xp[kt * 8 + quad * 2 + 1];
            float f[8] = {va.x, va.y, va.z, va.w, vb.x, vb.y, vb.z, vb.w};
            short8 h, lo8;
#pragma unroll
            for (int j = 0; j < 8; ++j) {
                unsigned short hh = f2bf(f[j]);
                h[j] = (short)hh;
                lo8[j] = (short)f2bf(f[j] - bf2f(hh));
            }
            bhi[nt][kt] = h;
            blo[nt][kt] = lo8;
        }
    }

    float best[2] = {3.4e38f, 3.4e38f};
    int bestk[2] = {0, 0};

    for (int c = 0; c < NCHUNK; ++c) {
        __syncthreads();
        {
            const uint4* gh = (const uint4*)(swhi + (size_t)c * 4096);
            const uint4* gl = (const uint4*)(swlo + (size_t)c * 4096);
            uint4* lh = (uint4*)As;
            lh[t] = gh[t];
            lh[256 + t] = gh[256 + t];
            lh[512 + t] = gl[t];
            lh[768 + t] = gl[256 + t];
        }
        if (t < CHUNK) csq_s[t] = c_sq[c * CHUNK + t];
        __syncthreads();

        floatx4 acc[2][2];
#pragma unroll
        for (int mt = 0; mt < 2; ++mt)
#pragma unroll
            for (int nt = 0; nt < 2; ++nt) acc[mt][nt] = (floatx4){0.f, 0.f, 0.f, 0.f};

#pragma unroll
        for (int kt = 0; kt < 4; ++kt) {
#pragma unroll
            for (int mt = 0; mt < 2; ++mt) {
                int fo = (mt * 4 + kt) * 512 + l * 8;
                short8 ah = *(const short8*)&As[fo];
                short8 al = *(const short8*)&As[4096 + fo];
#pragma unroll
                for (int nt = 0; nt < 2; ++nt) {
                    acc[mt][nt] = __builtin_amdgcn_mfma_f32_16x16x32_bf16(ah, bhi[nt][kt], acc[mt][nt], 0, 0, 0);
                    acc[mt][nt] = __builtin_amdgcn_mfma_f32_16x16x32_bf16(ah, blo[nt][kt], acc[mt][nt], 0, 0, 0);
                    acc[mt][nt] = __builtin_amdgcn_mfma_f32_16x16x32_bf16(al, bhi[nt][kt], acc[mt][nt], 0, 0, 0);
                }
            }
        }
#pragma unroll
        for (int mt = 0; mt < 2; ++mt) {
#pragma unroll
            for (int r = 0; r < 4; ++r) {
                float cs = csq_s[mt * 16 + quad * 4 + r];
                int kg = c * CHUNK + mt * 16 + quad * 4 + r;
#pragma unroll
                for (int nt = 0; nt < 2; ++nt) {
                    float d2 = xsqv[nt] - 2.f * acc[mt][nt][r] + cs;
                    if (d2 < best[nt]) { best[nt] = d2; bestk[nt] = kg; }
                }
            }
        }
    }

#pragma unroll
    for (int nt = 0; nt < 2; ++nt) {
#pragma unroll
        for (int off = 16; off < 64; off <<= 1) {
            float ob = __shfl_xor(best[nt], off);
            int ok = __shfl_xor(bestk[nt], off);
            if (ob < best[nt] || (ob == best[nt] && ok < bestk[nt])) {
                best[nt] = ob;
                bestk[nt] = ok;
            }
        }
    }
    if (quad == 0) {
#pragma unroll
        for (int nt = 0; nt < 2; ++nt) {
            labels[S0 + w * 32 + nt * 16 + l15] = (float)bestk[nt];
            atomicAdd(&lhist[bestk[nt]], 1);
        }
    }

    float contrib = (quad == 0) ? (fmaxf(best[0], 0.f) + fmaxf(best[1], 0.f)) : 0.f;
#pragma unroll
    for (int off = 32; off > 0; off >>= 1) contrib += __shfl_down(contrib, off);
    if (l == 0) red[w] = contrib;
    __syncthreads();
    if (t == 0) atomicAdd(inertia, red[0] + red[1] + red[2] + red[3]);

    for (int i = t; i < N_K; i += 256) {
        int v = lhist[i];
        if (v) atomicAdd(&ihist[i], v);
    }
}

// ---------------------------------------------------------------------------
// scan (per iter, 1 block): exclusive prefix of ihist -> offsets, cursor;
// counts as float.
// ---------------------------------------------------------------------------
__global__ __launch_bounds__(512) void scan_kernel(const int* __restrict__ ihist,
                                                   int* __restrict__ offsets,
                                                   int* __restrict__ cursor,
                                                   float* __restrict__ counts_f) {
    __shared__ int tmp[N_K];
    int t = threadIdx.x;
    int v = ihist[t];
    counts_f[t] = (float)v;
    int x = v;
    tmp[t] = x;
    __syncthreads();
    for (int off = 1; off < N_K; off <<= 1) {
        int y = (t >= off) ? tmp[t - off] : 0;
        __syncthreads();
        x += y;
        tmp[t] = x;
        __syncthreads();
    }
    int excl = x - v;
    offsets[t] = excl;
    cursor[t] = excl;
}

// ---------------------------------------------------------------------------
// scatter (per iter): block-aggregated counting-sort scatter.
// LDS hist + rank; ONE global atomic per distinct cluster per block.
// ---------------------------------------------------------------------------
__global__ __launch_bounds__(256) void scatter_kernel(const float* __restrict__ labels,
                                                      int* __restrict__ cursor,
                                                      int* __restrict__ order) {
    __shared__ int lhist[N_K];
    __shared__ int lbase[N_K];
    int t = threadIdx.x;
    int i = blockIdx.x * 256 + t;
    for (int j = t; j < N_K; j += 256) lhist[j] = 0;
    __syncthreads();
    int k = 0, rank = 0;
    bool valid = (i < N_S);
    if (valid) {
        k = (int)labels[i];
        rank = atomicAdd(&lhist[k], 1);
    }
    __syncthreads();
    for (int j = t; j < N_K; j += 256) {
        int c = lhist[j];
        lbase[j] = c ? atomicAdd(&cursor[j], c) : 0;
    }
    __syncthreads();
    if (valid) order[lbase[k] + rank] = i;
}

// ---------------------------------------------------------------------------
// csum (per iter): balanced window partition of order[].
// Each block owns 128 consecutive order[] entries (cluster-agnostic);
// offsets in LDS -> segment walk; 8 independent row loads in flight.
// ---------------------------------------------------------------------------
#define RPB 128
__global__ __launch_bounds__(256) void csum_kernel(const float* __restrict__ X,
                                                   const int* __restrict__ order,
                                                   const int* __restrict__ offsets,
                                                   float* __restrict__ sums) {
    __shared__ int offs_s[N_K + 1];
    __shared__ int ord_s[RPB];
    int t = threadIdx.x;
    int r0 = blockIdx.x * RPB;

    offs_s[t] = offsets[t];
    offs_s[t + 256] = (t + 256 < N_K) ? offsets[t + 256] : N_S;
    if (t == 255) offs_s[N_K] = N_S;
    if (t < RPB) ord_s[t] = order[r0 + t];
    __syncthreads();

    int st = t >> 7, d = t & 127;
    int rstart = r0 + st * 64;
    int rend = rstart + 64;
    const float* Xd = X + d;

    // largest k with offs_s[k] <= rstart
    int lo = 0, hi = N_K;
    while (hi - lo > 1) {
        int mid = (lo + hi) >> 1;
        if (offs_s[mid] <= rstart) lo = mid;
        else hi = mid;
    }
    int k = lo;

    int r = rstart;
    while (r < rend) {
        while (offs_s[k + 1] <= r) ++k;  // skip empties / advance segment
        int seg_end = min(offs_s[k + 1], rend);
        float acc = 0.f;
        for (; r + 8 <= seg_end; r += 8) {
            int b = r - r0;
            float v0 = Xd[(long long)ord_s[b + 0] * N_F];
            float v1 = Xd[(long long)ord_s[b + 1] * N_F];
            float v2 = Xd[(long long)ord_s[b + 2] * N_F];
            float v3 = Xd[(long long)ord_s[b + 3] * N_F];
            float v4 = Xd[(long long)ord_s[b + 4] * N_F];
            float v5 = Xd[(long long)ord_s[b + 5] * N_F];
            float v6 = Xd[(long long)ord_s[b + 6] * N_F];
            float v7 = Xd[(long long)ord_s[b + 7] * N_F];
            acc += ((v0 + v1) + (v2 + v3)) + ((v4 + v5) + (v6 + v7));
        }
        for (; r < seg_end; ++r) acc += Xd[(long long)ord_s[r - r0] * N_F];
        atomicAdd(&sums[k * N_F + d], acc);
    }
}

// ---------------------------------------------------------------------------
// final update: cent = counts>0 ? sums/counts : cent
// ---------------------------------------------------------------------------
__global__ __launch_bounds__(128) void update_kernel(const float* __restrict__ sums,
                                                     const float* __restrict__ counts_f,
                                                     float* __restrict__ cent) {
    int k = blockIdx.x;
    int d = threadIdx.x;
    float c = counts_f[k];
    float s = sums[k * N_F + d];
    float old = cent[k * N_F + d];
    cent[k * N_F + d] = (c > 0.f) ? (s / c) : old;
}

extern "C" void kernel_launch(void* const* d_in, const int* in_sizes, int n_in,
                              void* d_out, int out_size, void* d_ws, size_t ws_size,
                              hipStream_t stream) {
    const float* X = (const float*)d_in[0];
    const float* initc = (const float*)d_in[1];

    float* out = (float*)d_out;
    float* cent = out;                // [512*128] (output 0)
    float* labels = out + N_K * N_F;  // [400000]  (output 1)
    float* inertia = labels + N_S;    // [1]       (output 2)

    float* c_sq = (float*)d_ws;                      // 512 f
    float* sums = c_sq + N_K;                        // 65536 f
    float* counts_f = sums + N_K * N_F;              // 512 f
    float* xsq = counts_f + N_K;                     // 400000 f
    unsigned short* swhi = (unsigned short*)(xsq + N_S);  // 65536 ush
    unsigned short* swlo = swhi + N_K * N_F;              // 65536 ush
    int* ihist = (int*)(swlo + N_K * N_F);           // 512 i
    int* offsets = ihist + N_K;                      // 512 i
    int* cursor = offsets + N_K;                     // 512 i
    int* order = cursor + N_K;                       // 400000 i

    xsq_kernel<<<N_S / 64, 256, 0, stream>>>(X, xsq);
    for (int it = 0; it < ITERS; ++it) {
        prep_update_kernel<<<N_K, 64, 0, stream>>>(initc, cent, sums, counts_f, c_sq,
                                                   swhi, swlo, ihist, inertia, it > 0);
        assign_kernel<<<N_S / 128, 256, 0, stream>>>(X, swhi, swlo, c_sq, xsq,
                                                     labels, inertia, ihist);
        scan_kernel<<<1, N_K, 0, stream>>>(ihist, offsets, cursor, counts_f);
        scatter_kernel<<<(N_S + 255) / 256, 256, 0, stream>>>(labels, cursor, order);
        csum_kernel<<<N_S / RPB, 256, 0, stream>>>(X, order, offsets, sums);
    }
    update_kernel<<<N_K, N_F, 0, stream>>>(sums, counts_f, cent);
}

// Round 6
// 2167.945 us; speedup vs baseline: 8.5295x; 1.2122x over previous
//
#include <hip/hip_runtime.h>

#define N_S 400000
#define N_F 128
#define N_K 512
#define ITERS 10

typedef __attribute__((ext_vector_type(8))) short short8;
typedef __attribute__((ext_vector_type(4))) float floatx4;

__device__ inline unsigned short f2bf(float f) {
    unsigned int u = __float_as_uint(f);
    unsigned int r = (u + 0x7FFFu + ((u >> 16) & 1u)) >> 16;
    return (unsigned short)r;
}
__device__ inline float bf2f(unsigned short h) {
    return __uint_as_float(((unsigned int)h) << 16);
}

// Swizzled (MFMA-fragment-order) centroid storage, hi-only:
// cluster k, dim d -> frag ((k>>5)*8 + ((k>>4)&1)*4 + (d>>5)), lane quad*16+m, elem j
__device__ inline void put_sw(unsigned short* __restrict__ swhi, int k, int d, float v) {
    int c = k >> 5, mm = k & 31;
    int mt = mm >> 4, m = mm & 15;
    int kt = d >> 5, r = d & 31;
    int quad = r >> 3, j = r & 7;
    int lane = quad * 16 + m;
    int idx = ((c * 8 + mt * 4 + kt) * 64 + lane) * 8 + j;
    swhi[idx] = f2bf(v);
}

// ---------------------------------------------------------------------------
// xsq (once): x_sq[i] = ||X_i||^2 fp32 exact
// ---------------------------------------------------------------------------
__global__ __launch_bounds__(256) void xsq_kernel(const float* __restrict__ X,
                                                  float* __restrict__ xsq) {
    int wave = threadIdx.x >> 6, lane = threadIdx.x & 63;
    int row = blockIdx.x * 64 + wave * 16 + (lane >> 2);
    int qpart = lane & 3;
    const float4* xp = (const float4*)(X + (long long)row * N_F) + qpart * 8;
    float s = 0.f;
#pragma unroll
    for (int q = 0; q < 8; ++q) {
        float4 v = xp[q];
        s += v.x * v.x + v.y * v.y + v.z * v.z + v.w * v.w;
    }
    s += __shfl_xor(s, 1);
    s += __shfl_xor(s, 2);
    if (qpart == 0) xsq[row] = s;
}

// ---------------------------------------------------------------------------
// prep_update (per iter): [optional] cent = counts>0 ? sums/counts : cent;
// write fp32 cent, c_sq, swizzled bf16 hi; zero sums/ihist/inertia.
// ---------------------------------------------------------------------------
__global__ __launch_bounds__(64) void prep_update_kernel(
    const float* __restrict__ src, float* __restrict__ cent,
    float* __restrict__ sums, const float* __restrict__ counts_f,
    float* __restrict__ c_sq, unsigned short* __restrict__ swhi,
    int* __restrict__ ihist, float* __restrict__ inertia, int do_update) {
    int k = blockIdx.x, lane = threadIdx.x;
    float a, b;
    if (do_update) {
        float cnt = counts_f[k];
        float sa = sums[k * N_F + lane], sb = sums[k * N_F + 64 + lane];
        float olda = cent[k * N_F + lane], oldb = cent[k * N_F + 64 + lane];
        a = (cnt > 0.f) ? (sa / cnt) : olda;
        b = (cnt > 0.f) ? (sb / cnt) : oldb;
    } else {
        a = src[k * N_F + lane];
        b = src[k * N_F + 64 + lane];
    }
    cent[k * N_F + lane] = a;
    cent[k * N_F + 64 + lane] = b;
    sums[k * N_F + lane] = 0.f;
    sums[k * N_F + 64 + lane] = 0.f;
    put_sw(swhi, k, lane, a);
    put_sw(swhi, k, lane + 64, b);
    float s = fmaf(a, a, b * b);
#pragma unroll
    for (int off = 32; off > 0; off >>= 1) s += __shfl_down(s, off);
    if (lane == 0) {
        c_sq[k] = s;
        ihist[k] = 0;
        if (k == 0) *inertia = 0.f;
    }
}

// ---------------------------------------------------------------------------
// assign v4: single-product bf16 MFMA, A streamed global->reg (L2-resident,
// fragment-ordered), B = 64 samples/wave in regs, NO barriers in main loop.
// argmin on d2' = c_sq - 2*dot (x_sq folded in only for inertia).
// ---------------------------------------------------------------------------
#define CHUNK 32
#define NCHUNK (N_K / CHUNK)
#define NTN 4  // n-tiles per wave (64 samples)

__global__ __launch_bounds__(256, 3) void assign_kernel(
    const float* __restrict__ X,
    const unsigned short* __restrict__ swhi,
    const float* __restrict__ c_sq,
    const float* __restrict__ x_sq,
    float* __restrict__ labels,
    float* __restrict__ inertia,
    int* __restrict__ ihist) {
    __shared__ __align__(16) float csq_s[N_K];
    __shared__ int lhist[N_K];
    __shared__ float red[4];

    int t = threadIdx.x;
    int w = t >> 6, l = t & 63;
    int quad = l >> 4, l15 = l & 15;
    long long S0 = (long long)blockIdx.x * 256;

    for (int i = t; i < N_K; i += 256) {
        lhist[i] = 0;
        csq_s[i] = c_sq[i];
    }

    // B fragments (bf16 hi) + xsq, direct from global; tail rows clamped.
    short8 bhi[NTN][4];
    float xsqv[NTN];
    long long srow[NTN];
#pragma unroll
    for (int nt = 0; nt < NTN; ++nt) {
        long long s = S0 + w * 64 + nt * 16 + l15;
        srow[nt] = s;
        long long ss = (s < N_S) ? s : (N_S - 1);
        xsqv[nt] = x_sq[ss];
        const float4* xp = (const float4*)(X + ss * N_F);
#pragma unroll
        for (int kt = 0; kt < 4; ++kt) {
            float4 va = xp[kt * 8 + quad * 2];
            float4 vb = xp[kt * 8 + quad * 2 + 1];
            float f[8] = {va.x, va.y, va.z, va.w, vb.x, vb.y, vb.z, vb.w};
            short8 h;
#pragma unroll
            for (int j = 0; j < 8; ++j) h[j] = (short)f2bf(f[j]);
            bhi[nt][kt] = h;
        }
    }
    __syncthreads();

    float best[NTN];
    int bestk[NTN];
#pragma unroll
    for (int nt = 0; nt < NTN; ++nt) { best[nt] = 3.4e38f; bestk[nt] = 0; }

    const short8* ap = (const short8*)swhi + l;  // + (c*8 + mt*4 + kt)*64

    for (int c = 0; c < NCHUNK; ++c) {
        floatx4 acc[2][NTN];
#pragma unroll
        for (int mt = 0; mt < 2; ++mt)
#pragma unroll
            for (int nt = 0; nt < NTN; ++nt) acc[mt][nt] = (floatx4){0.f, 0.f, 0.f, 0.f};

#pragma unroll
        for (int kt = 0; kt < 4; ++kt) {
            short8 a0 = ap[(kt) * 64];
            short8 a1 = ap[(4 + kt) * 64];
#pragma unroll
            for (int nt = 0; nt < NTN; ++nt) {
                acc[0][nt] = __builtin_amdgcn_mfma_f32_16x16x32_bf16(a0, bhi[nt][kt], acc[0][nt], 0, 0, 0);
                acc[1][nt] = __builtin_amdgcn_mfma_f32_16x16x32_bf16(a1, bhi[nt][kt], acc[1][nt], 0, 0, 0);
            }
        }
        ap += 8 * 64;

#pragma unroll
        for (int mt = 0; mt < 2; ++mt) {
            float4 cs = ((const float4*)csq_s)[c * 8 + mt * 4 + quad];
#pragma unroll
            for (int r = 0; r < 4; ++r) {
                float csr = (r == 0) ? cs.x : (r == 1) ? cs.y : (r == 2) ? cs.z : cs.w;
                int kg = c * CHUNK + mt * 16 + quad * 4 + r;
#pragma unroll
                for (int nt = 0; nt < NTN; ++nt) {
                    float d2 = fmaf(-2.f, acc[mt][nt][r], csr);
                    if (d2 < best[nt]) { best[nt] = d2; bestk[nt] = kg; }
                }
            }
        }
    }

    // combine 4 quads per sample column (tie -> smaller k)
#pragma unroll
    for (int nt = 0; nt < NTN; ++nt) {
#pragma unroll
        for (int off = 16; off < 64; off <<= 1) {
            float ob = __shfl_xor(best[nt], off);
            int ok = __shfl_xor(bestk[nt], off);
            if (ob < best[nt] || (ob == best[nt] && ok < bestk[nt])) {
                best[nt] = ob;
                bestk[nt] = ok;
            }
        }
    }

    float contrib = 0.f;
    if (quad == 0) {
#pragma unroll
        for (int nt = 0; nt < NTN; ++nt) {
            if (srow[nt] < N_S) {
                labels[srow[nt]] = (float)bestk[nt];
                atomicAdd(&lhist[bestk[nt]], 1);
                contrib += fmaxf(xsqv[nt] + best[nt], 0.f);
            }
        }
    }
#pragma unroll
    for (int off = 32; off > 0; off >>= 1) contrib += __shfl_down(contrib, off);
    if (l == 0) red[w] = contrib;
    __syncthreads();
    if (t == 0) atomicAdd(inertia, red[0] + red[1] + red[2] + red[3]);

    for (int i = t; i < N_K; i += 256) {
        int v = lhist[i];
        if (v) atomicAdd(&ihist[i], v);
    }
}

// ---------------------------------------------------------------------------
// scan (per iter, 1 block): exclusive prefix of ihist -> offsets, cursor.
// ---------------------------------------------------------------------------
__global__ __launch_bounds__(512) void scan_kernel(const int* __restrict__ ihist,
                                                   int* __restrict__ offsets,
                                                   int* __restrict__ cursor,
                                                   float* __restrict__ counts_f) {
    __shared__ int tmp[N_K];
    int t = threadIdx.x;
    int v = ihist[t];
    counts_f[t] = (float)v;
    int x = v;
    tmp[t] = x;
    __syncthreads();
    for (int off = 1; off < N_K; off <<= 1) {
        int y = (t >= off) ? tmp[t - off] : 0;
        __syncthreads();
        x += y;
        tmp[t] = x;
        __syncthreads();
    }
    int excl = x - v;
    offsets[t] = excl;
    cursor[t] = excl;
}

// ---------------------------------------------------------------------------
// scatter (per iter): block-aggregated counting-sort scatter.
// ---------------------------------------------------------------------------
__global__ __launch_bounds__(256) void scatter_kernel(const float* __restrict__ labels,
                                                      int* __restrict__ cursor,
                                                      int* __restrict__ order) {
    __shared__ int lhist[N_K];
    __shared__ int lbase[N_K];
    int t = threadIdx.x;
    int i = blockIdx.x * 256 + t;
    for (int j = t; j < N_K; j += 256) lhist[j] = 0;
    __syncthreads();
    int k = 0, rank = 0;
    bool valid = (i < N_S);
    if (valid) {
        k = (int)labels[i];
        rank = atomicAdd(&lhist[k], 1);
    }
    __syncthreads();
    for (int j = t; j < N_K; j += 256) {
        int c = lhist[j];
        lbase[j] = c ? atomicAdd(&cursor[j], c) : 0;
    }
    __syncthreads();
    if (valid) order[lbase[k] + rank] = i;
}

// ---------------------------------------------------------------------------
// csum (per iter): balanced window partition of order[] (cluster-agnostic).
// ---------------------------------------------------------------------------
#define RPB 128
__global__ __launch_bounds__(256) void csum_kernel(const float* __restrict__ X,
                                                   const int* __restrict__ order,
                                                   const int* __restrict__ offsets,
                                                   float* __restrict__ sums) {
    __shared__ int offs_s[N_K + 1];
    __shared__ int ord_s[RPB];
    int t = threadIdx.x;
    int r0 = blockIdx.x * RPB;

    offs_s[t] = offsets[t];
    offs_s[t + 256] = (t + 256 < N_K) ? offsets[t + 256] : N_S;
    if (t == 255) offs_s[N_K] = N_S;
    if (t < RPB) ord_s[t] = order[r0 + t];
    __syncthreads();

    int st = t >> 7, d = t & 127;
    int rstart = r0 + st * 64;
    int rend = rstart + 64;
    const float* Xd = X + d;

    int lo = 0, hi = N_K;
    while (hi - lo > 1) {
        int mid = (lo + hi) >> 1;
        if (offs_s[mid] <= rstart) lo = mid;
        else hi = mid;
    }
    int k = lo;

    int r = rstart;
    while (r < rend) {
        while (offs_s[k + 1] <= r) ++k;
        int seg_end = min(offs_s[k + 1], rend);
        float acc = 0.f;
        for (; r + 8 <= seg_end; r += 8) {
            int b = r - r0;
            float v0 = Xd[(long long)ord_s[b + 0] * N_F];
            float v1 = Xd[(long long)ord_s[b + 1] * N_F];
            float v2 = Xd[(long long)ord_s[b + 2] * N_F];
            float v3 = Xd[(long long)ord_s[b + 3] * N_F];
            float v4 = Xd[(long long)ord_s[b + 4] * N_F];
            float v5 = Xd[(long long)ord_s[b + 5] * N_F];
            float v6 = Xd[(long long)ord_s[b + 6] * N_F];
            float v7 = Xd[(long long)ord_s[b + 7] * N_F];
            acc += ((v0 + v1) + (v2 + v3)) + ((v4 + v5) + (v6 + v7));
        }
        for (; r < seg_end; ++r) acc += Xd[(long long)ord_s[r - r0] * N_F];
        atomicAdd(&sums[k * N_F + d], acc);
    }
}

// ---------------------------------------------------------------------------
// final update: cent = counts>0 ? sums/counts : cent
// ---------------------------------------------------------------------------
__global__ __launch_bounds__(128) void update_kernel(const float* __restrict__ sums,
                                                     const float* __restrict__ counts_f,
                                                     float* __restrict__ cent) {
    int k = blockIdx.x;
    int d = threadIdx.x;
    float c = counts_f[k];
    float s = sums[k * N_F + d];
    float old = cent[k * N_F + d];
    cent[k * N_F + d] = (c > 0.f) ? (s / c) : old;
}

extern "C" void kernel_launch(void* const* d_in, const int* in_sizes, int n_in,
                              void* d_out, int out_size, void* d_ws, size_t ws_size,
                              hipStream_t stream) {
    const float* X = (const float*)d_in[0];
    const float* initc = (const float*)d_in[1];

    float* out = (float*)d_out;
    float* cent = out;                // [512*128] (output 0)
    float* labels = out + N_K * N_F;  // [400000]  (output 1)
    float* inertia = labels + N_S;    // [1]       (output 2)

    float* c_sq = (float*)d_ws;                      // 512 f
    float* sums = c_sq + N_K;                        // 65536 f
    float* counts_f = sums + N_K * N_F;              // 512 f
    float* xsq = counts_f + N_K;                     // 400000 f
    unsigned short* swhi = (unsigned short*)(xsq + N_S);  // 65536 ush
    int* ihist = (int*)(swhi + N_K * N_F);           // 512 i
    int* offsets = ihist + N_K;                      // 512 i
    int* cursor = offsets + N_K;                     // 512 i
    int* order = cursor + N_K;                       // 400000 i

    xsq_kernel<<<N_S / 64, 256, 0, stream>>>(X, xsq);
    for (int it = 0; it < ITERS; ++it) {
        prep_update_kernel<<<N_K, 64, 0, stream>>>(initc, cent, sums, counts_f, c_sq,
                                                   swhi, ihist, inertia, it > 0);
        assign_kernel<<<(N_S + 255) / 256, 256, 0, stream>>>(X, swhi, c_sq, xsq,
                                                             labels, inertia, ihist);
        scan_kernel<<<1, N_K, 0, stream>>>(ihist, offsets, cursor, counts_f);
        scatter_kernel<<<(N_S + 255) / 256, 256, 0, stream>>>(labels, cursor, order);
        csum_kernel<<<N_S / RPB, 256, 0, stream>>>(X, order, offsets, sums);
    }
    update_kernel<<<N_K, N_F, 0, stream>>>(sums, counts_f, cent);
}